// Round 1
// baseline (7444.560 us; speedup 1.0000x reference)
//
#include <hip/hip_runtime.h>

#define BB 256
#define TT 256
#define II 512
#define HH 1024

typedef _Float16 h16;
typedef __attribute__((ext_vector_type(4))) _Float16 h16x4;
typedef __attribute__((ext_vector_type(8))) _Float16 h16x8;
typedef __attribute__((ext_vector_type(4))) float f32x4;

#define KPADH 1032
#define SMEM_BYTES 149504  // 64*1032*2 (Abuf) + 4*64*17*4 (Pre)

// workspace layout (bytes)
#define WX_OFF   0UL
#define WH_OFF   4194304UL
#define BIAS_OFF 12582912UL
#define W1T_OFF  12599296UL
#define HBUF_OFF 12861440UL
#define ARR_OFF  13385728UL
#define XH_OFF   13389824UL
#define XH_END   80498688UL

__device__ __forceinline__ float sigm(float x) { return 1.0f / (1.0f + __expf(-x)); }
__device__ __forceinline__ float tanh_(float x) { float e = __expf(2.0f * x); return 1.0f - 2.0f / (e + 1.0f); }

// ---------------- prep: cast/pack weights ----------------
__global__ void k_prep(const float* __restrict__ Wfx, const float* __restrict__ Wfh, const float* __restrict__ bf,
                       const float* __restrict__ Wix, const float* __restrict__ Wih, const float* __restrict__ bi,
                       const float* __restrict__ Wox, const float* __restrict__ Woh, const float* __restrict__ bo,
                       const float* __restrict__ Wcx, const float* __restrict__ Wch, const float* __restrict__ bc,
                       const float* __restrict__ W1,
                       h16* __restrict__ Wx, h16* __restrict__ Wh, float* __restrict__ bias, float* __restrict__ W1T)
{
  const long NWX = 4096L * 512, NWH = 4096L * 1024, NB = 4096, NW1 = 1024L * 64;
  const long total = NWX + NWH + NB + NW1;
  for (long id = blockIdx.x * 256L + threadIdx.x; id < total; id += gridDim.x * 256L) {
    if (id < NWX) {
      long n = id >> 9, k = id & 511;
      long g = n >> 10, j = n & 1023;
      const float* s = (g == 0) ? Wfx : (g == 1) ? Wix : (g == 2) ? Wox : Wcx;
      Wx[id] = (h16)s[j * II + k];
    } else if (id < NWX + NWH) {
      long i2 = id - NWX;
      long n = i2 >> 10, k = i2 & 1023;
      long g = n >> 10, j = n & 1023;
      const float* s = (g == 0) ? Wfh : (g == 1) ? Wih : (g == 2) ? Woh : Wch;
      Wh[i2] = (h16)s[j * HH + k];
    } else if (id < NWX + NWH + NB) {
      long n = id - NWX - NWH;
      long g = n >> 10, j = n & 1023;
      const float* s = (g == 0) ? bf : (g == 1) ? bi : (g == 2) ? bo : bc;
      bias[n] = s[j];
    } else {
      long i2 = id - NWX - NWH - NB;
      long k = i2 >> 6, n = i2 & 63;
      W1T[i2] = W1[n * HH + k];
    }
  }
}

// ---------------- prep: cast x to fp16 ----------------
__global__ void k_castx(const float* __restrict__ x, h16* __restrict__ xh) {
  const long n = (long)BB * TT * II;
  for (long i = (blockIdx.x * 256L + threadIdx.x) * 4; i < n; i += gridDim.x * 1024L) {
    float4 v = *(const float4*)(x + i);
    h16x4 o = {(h16)v.x, (h16)v.y, (h16)v.z, (h16)v.w};
    *(h16x4*)(xh + i) = o;
  }
}

// ---------------- persistent LSTM kernel ----------------
// grid 256 WGs x 256 thr. 4 groups x 64 rows; per WG: 16 H-cols x 4 gates.
// 146KB LDS forces 1 WG/CU -> all 256 co-resident -> group barriers safe.
template <int USE_XH>
__global__ __launch_bounds__(256, 1) void k_lstm(
    const float* __restrict__ x32, const h16* __restrict__ x16,
    const h16* __restrict__ Wx, const h16* __restrict__ Wh,
    const float* __restrict__ bias,
    h16* __restrict__ hbuf, unsigned int* __restrict__ arr)
{
  extern __shared__ char smem[];
  h16* Abuf = (h16*)smem;               // [64][KPADH] fp16
  float* Pre = (float*)(smem + 132096); // [4][64][17] f32

  const int tid = threadIdx.x;
  const int wid = tid >> 6;
  const int lane = tid & 63;
  const int lm = lane & 15;   // MFMA row/col within 16
  const int lq = lane >> 4;   // k-quad

  const int bx = blockIdx.x;
  const int idx = bx >> 3;
  const int nslice = (bx & 7) * 8 + (idx & 7);  // XCD-affinity swizzle (perf only)
  const int group = idx >> 3;                   // 0..3
  const int r0 = group * 64;
  const int hc0 = nslice * 16;

  const int mhalf = (wid >> 1) * 32;  // 0 / 32
  const int gpair = (wid & 1) * 2;    // gates {0,1} or {2,3}

  const h16* WhB[2]; const h16* WxB[2]; float bsv[2];
#pragma unroll
  for (int nt = 0; nt < 2; ++nt) {
    int ng = (gpair + nt) * HH + hc0 + lm;   // row of packed [4096 x K] weight
    WhB[nt] = Wh + (size_t)ng * HH + lq * 8;
    WxB[nt] = Wx + (size_t)ng * II + lq * 8;
    bsv[nt] = bias[ng];
  }
  const float* xr32[2]; const h16* xr16[2];
#pragma unroll
  for (int mt = 0; mt < 2; ++mt) {
    size_t row = (size_t)(r0 + mhalf + mt * 16 + lm);
    xr32[mt] = x32 + row * ((size_t)TT * II) + lq * 8;
    xr16[mt] = x16 + row * ((size_t)TT * II) + lq * 8;
  }
  const int aBaseH = (mhalf + lm) * KPADH + lq * 8;

  const int ucol = tid & 15;
  const int urow0 = (tid >> 4) * 4;
  float cst[4] = {0.f, 0.f, 0.f, 0.f};

  unsigned int* flag = arr + group * TT;

  for (int t = 0; t < TT; ++t) {
    f32x4 acc[2][2];
#pragma unroll
    for (int mt = 0; mt < 2; ++mt)
#pragma unroll
      for (int nt = 0; nt < 2; ++nt)
        acc[mt][nt] = (f32x4){bsv[nt], bsv[nt], bsv[nt], bsv[nt]};

    // ---- x-part (independent of h; overlaps the barrier wait below) ----
#pragma unroll 4
    for (int kk = 0; kk < II / 32; ++kk) {
      h16x8 a0, a1;
      if (USE_XH) {
        a0 = *(const h16x8*)(xr16[0] + (size_t)t * II + kk * 32);
        a1 = *(const h16x8*)(xr16[1] + (size_t)t * II + kk * 32);
      } else {
        const float* p0 = xr32[0] + (size_t)t * II + kk * 32;
        const float* p1 = xr32[1] + (size_t)t * II + kk * 32;
        float4 u0 = *(const float4*)(p0), v0 = *(const float4*)(p0 + 4);
        float4 u1 = *(const float4*)(p1), v1 = *(const float4*)(p1 + 4);
        a0 = (h16x8){(h16)u0.x, (h16)u0.y, (h16)u0.z, (h16)u0.w, (h16)v0.x, (h16)v0.y, (h16)v0.z, (h16)v0.w};
        a1 = (h16x8){(h16)u1.x, (h16)u1.y, (h16)u1.z, (h16)u1.w, (h16)v1.x, (h16)v1.y, (h16)v1.z, (h16)v1.w};
      }
      h16x8 b0 = *(const h16x8*)(WxB[0] + kk * 32);
      h16x8 b1 = *(const h16x8*)(WxB[1] + kk * 32);
      acc[0][0] = __builtin_amdgcn_mfma_f32_16x16x32_f16(a0, b0, acc[0][0], 0, 0, 0);
      acc[0][1] = __builtin_amdgcn_mfma_f32_16x16x32_f16(a0, b1, acc[0][1], 0, 0, 0);
      acc[1][0] = __builtin_amdgcn_mfma_f32_16x16x32_f16(a1, b0, acc[1][0], 0, 0, 0);
      acc[1][1] = __builtin_amdgcn_mfma_f32_16x16x32_f16(a1, b1, acc[1][1], 0, 0, 0);
    }

    if (t > 0) {
      // ---- group barrier: wait for h(t-1) ----
      if (tid == 0) {
        while (__hip_atomic_load(flag + (t - 1), __ATOMIC_RELAXED, __HIP_MEMORY_SCOPE_AGENT) < 64u)
          __builtin_amdgcn_s_sleep(1);
      }
      __syncthreads();
      __builtin_amdgcn_fence(__ATOMIC_ACQUIRE, "agent");
      // ---- stage h(t-1) -> LDS ----
      const h16* hs = hbuf + (size_t)r0 * HH;
#pragma unroll 4
      for (int c = tid; c < 64 * 128; c += 256) {
        int r = c >> 7, col = c & 127;
        h16x8 v = *(const h16x8*)(hs + r * HH + col * 8);
        *(h16x8*)(Abuf + r * KPADH + col * 8) = v;
      }
      __syncthreads();
      // ---- h-part GEMM ----
#pragma unroll 4
      for (int kk = 0; kk < HH / 32; ++kk) {
        h16x8 a0 = *(const h16x8*)(Abuf + aBaseH + kk * 32);
        h16x8 a1 = *(const h16x8*)(Abuf + aBaseH + 16 * KPADH + kk * 32);
        h16x8 b0 = *(const h16x8*)(WhB[0] + kk * 32);
        h16x8 b1 = *(const h16x8*)(WhB[1] + kk * 32);
        acc[0][0] = __builtin_amdgcn_mfma_f32_16x16x32_f16(a0, b0, acc[0][0], 0, 0, 0);
        acc[0][1] = __builtin_amdgcn_mfma_f32_16x16x32_f16(a0, b1, acc[0][1], 0, 0, 0);
        acc[1][0] = __builtin_amdgcn_mfma_f32_16x16x32_f16(a1, b0, acc[1][0], 0, 0, 0);
        acc[1][1] = __builtin_amdgcn_mfma_f32_16x16x32_f16(a1, b1, acc[1][1], 0, 0, 0);
      }
    }

    // ---- epilogue: preacts -> LDS (cross-wave gate exchange) ----
#pragma unroll
    for (int mt = 0; mt < 2; ++mt)
#pragma unroll
      for (int nt = 0; nt < 2; ++nt) {
        int gate = gpair + nt;
#pragma unroll
        for (int i = 0; i < 4; ++i) {
          int row = mhalf + mt * 16 + lq * 4 + i;
          Pre[(gate * 64 + row) * 17 + lm] = acc[mt][nt][i];
        }
      }
    __syncthreads();
    // ---- elementwise c/h update (c persistent in regs) ----
#pragma unroll
    for (int j = 0; j < 4; ++j) {
      int row = urow0 + j;
      float fp = Pre[(0 * 64 + row) * 17 + ucol];
      float ip = Pre[(1 * 64 + row) * 17 + ucol];
      float op = Pre[(2 * 64 + row) * 17 + ucol];
      float cp = Pre[(3 * 64 + row) * 17 + ucol];
      float c2 = sigm(fp) * cst[j] + sigm(ip) * tanh_(cp);
      cst[j] = c2;
      float hv = sigm(op) * tanh_(c2);
      hbuf[(size_t)(r0 + row) * HH + hc0 + ucol] = (h16)hv;
    }
    __builtin_amdgcn_s_waitcnt(0);
    __syncthreads();  // all waves' h stores drained to L2 before release
    if (tid == 0)
      __hip_atomic_fetch_add(flag + t, 1u, __ATOMIC_RELEASE, __HIP_MEMORY_SCOPE_AGENT);
  }
}

// ---------------- head: relu -> [64] relu -> [10] softmax ----------------
__global__ void k_head(const h16* __restrict__ hbuf, const float* __restrict__ W1T,
                       const float* __restrict__ b1, const float* __restrict__ W2,
                       const float* __restrict__ b2, float* __restrict__ out)
{
  __shared__ float hrow[1024];
  __shared__ float part[64][5];
  __shared__ float h1[64];
  __shared__ float logit[10];
  int r = blockIdx.x, tid = threadIdx.x;
  for (int i = tid; i < 1024; i += 256) {
    float v = (float)hbuf[(size_t)r * HH + i];
    hrow[i] = v > 0.f ? v : 0.f;
  }
  __syncthreads();
  int n = tid & 63, q = tid >> 6;
  float s = 0.f;
  for (int i = 0; i < 256; ++i) s += hrow[q * 256 + i] * W1T[(q * 256 + i) * 64 + n];
  part[n][q] = s;
  __syncthreads();
  if (tid < 64) {
    float v = part[tid][0] + part[tid][1] + part[tid][2] + part[tid][3] + b1[tid];
    h1[tid] = v > 0.f ? v : 0.f;
  }
  __syncthreads();
  if (tid < 10) {
    float s2 = b2[tid];
    for (int k = 0; k < 64; ++k) s2 += h1[k] * W2[tid * 64 + k];
    logit[tid] = s2;
  }
  __syncthreads();
  if (tid < 10) {
    float m = logit[0];
    for (int i = 1; i < 10; ++i) m = fmaxf(m, logit[i]);
    float sum = 0.f;
    for (int i = 0; i < 10; ++i) sum += __expf(logit[i] - m);
    out[r * 10 + tid] = __expf(logit[tid] - m) / sum;
  }
}

extern "C" void kernel_launch(void* const* d_in, const int* in_sizes, int n_in,
                              void* d_out, int out_size, void* d_ws, size_t ws_size,
                              hipStream_t stream) {
  const float* x   = (const float*)d_in[0];
  const float* Wfx = (const float*)d_in[1];
  const float* Wfh = (const float*)d_in[2];
  const float* bf  = (const float*)d_in[3];
  const float* Wix = (const float*)d_in[4];
  const float* Wih = (const float*)d_in[5];
  const float* bi  = (const float*)d_in[6];
  const float* Wox = (const float*)d_in[7];
  const float* Woh = (const float*)d_in[8];
  const float* bo  = (const float*)d_in[9];
  const float* Wcx = (const float*)d_in[10];
  const float* Wch = (const float*)d_in[11];
  const float* bc  = (const float*)d_in[12];
  const float* W1  = (const float*)d_in[13];
  const float* b1  = (const float*)d_in[14];
  const float* W2  = (const float*)d_in[15];
  const float* b2  = (const float*)d_in[16];
  (void)in_sizes; (void)n_in; (void)out_size;

  char* ws = (char*)d_ws;
  h16* Wx = (h16*)(ws + WX_OFF);
  h16* Wh = (h16*)(ws + WH_OFF);
  float* bias = (float*)(ws + BIAS_OFF);
  float* W1T = (float*)(ws + W1T_OFF);
  h16* hbuf = (h16*)(ws + HBUF_OFF);
  unsigned int* arr = (unsigned int*)(ws + ARR_OFF);
  h16* xh = (h16*)(ws + XH_OFF);
  const int use_xh = (ws_size >= XH_END) ? 1 : 0;

  hipMemsetAsync(arr, 0, 4096, stream);
  k_prep<<<4096, 256, 0, stream>>>(Wfx, Wfh, bf, Wix, Wih, bi, Wox, Woh, bo, Wcx, Wch, bc, W1,
                                   Wx, Wh, bias, W1T);
  if (use_xh) k_castx<<<8192, 256, 0, stream>>>(x, xh);

  (void)hipFuncSetAttribute(reinterpret_cast<const void*>(&k_lstm<1>),
                            hipFuncAttributeMaxDynamicSharedMemorySize, SMEM_BYTES);
  (void)hipFuncSetAttribute(reinterpret_cast<const void*>(&k_lstm<0>),
                            hipFuncAttributeMaxDynamicSharedMemorySize, SMEM_BYTES);
  if (use_xh)
    k_lstm<1><<<256, 256, SMEM_BYTES, stream>>>(x, xh, Wx, Wh, bias, hbuf, arr);
  else
    k_lstm<0><<<256, 256, SMEM_BYTES, stream>>>(x, xh, Wx, Wh, bias, hbuf, arr);

  k_head<<<256, 256, 0, stream>>>(hbuf, W1T, b1, W2, b2, (float*)d_out);
}